// Round 10
// baseline (5008.534 us; speedup 1.0000x reference)
//
#include <hip/hip_runtime.h>

// 16-qubit statevector, 512 samples, 6 StronglyEntanglingLayers, qubit q <-> bit q.
// Round 17: all-cheap-rot schedule (r9) with Q's memory morphology FIXED.
// r9 evidence: Q's 8B scalar access (pair bit a8 at p11) caused 1.75x write
// amplification + read RMW (FETCH 115MB, WRITE 229MB) -> 122us; P (dense 16B,
// all-cheap rots) was ~20-35us. Fix: Q takes 64 amps/thread with locals
// {a0, a8-12} so its pair bit a0 sits at p0 -> float4 loads, every wave
// instruction 1KB dense. Slot arithmetic: P (5 locals + tid3-5) hosts
// R(0-4),R(5-7); Q (6 locals + tid3-5) hosts R(8-12),R(13-15). ZERO rots on
// tid0-2 (the r2-r8 slow-kernel invariant) and zero on wave/fixed bits.
//
// Tilings (r = l+1), one phys layout for all kernels:
//   phys: p0=a0 | p1-3=a5-7 | p4-6=a13-15 | p7-10=a1-4 | p11-13=a8-10 | p14-15=a11-12
//   P(l) [32 amps]: E=a0-4 | tid3-5=a5-7 | tid0-2=a13-15 | waves=a8-10 | fb=a11-12.
//        wraps_{l-1} (t=0..l-1 local, c=16-l+k in a11-15 -> ibase), R_l(0..4) local,
//        R_l(5,6,7) lane masks 8,16,32, prefix g=0..7-r (t=r..7).
//   Q(l) [64 amps]: E=a0,a8-12 | tid0-2=a5-7 | tid3-5=a13-15 | waves=a1-3 | fb=a4.
//        R_l(8..12) local (m-bits), R_l(13..15) lane masks 8,16,32,
//        mid g=8-r..15-r (t=8..15; controls local-static or ibase).
//   P(0): init = product of Rot_0(q)*RX(x_q)|0> (all 16 rots folded) + prefix.
//   finalK: wraps_5 (t=0..5, c=10..15) + measurement. P-tiling.
// Chunk = 256 samples (128 MB).

#define NTH 512
typedef float v32f __attribute__((ext_vector_type(32)));

template <int I> struct IC { static constexpr int value = I; };
template <int N, int I = 0, typename F>
__device__ __forceinline__ void static_for(F&& f) {
  if constexpr (I < N) { f(IC<I>{}); static_for<N, I + 1>(f); }
}

// ---------------- P-side helpers: 32 amps, locals a0-4 ----------------

template <int LB>  // Rot on local e-bit LB (qubit LB)
__device__ __forceinline__ void rot_local(v32f& ar, v32f& ai, const float* __restrict__ u) {
  const float u00r = u[0], u00i = u[1], u01r = u[2], u01i = u[3];
  const float u10r = u[4], u10i = u[5], u11r = u[6], u11i = u[7];
  static_for<16>([&](auto hc) {
    constexpr int h = hc.value;
    constexpr int e0 = ((h >> LB) << (LB + 1)) | (h & ((1 << LB) - 1));
    constexpr int e1 = e0 | (1 << LB);
    const float axr = ar[e0], axi = ai[e0], bxr = ar[e1], bxi = ai[e1];
    ar[e0] = u00r * axr - u00i * axi + u01r * bxr - u01i * bxi;
    ai[e0] = u00r * axi + u00i * axr + u01r * bxi + u01i * bxr;
    ar[e1] = u10r * axr - u10i * axi + u11r * bxr - u11i * bxi;
    ai[e1] = u10r * axi + u10i * axr + u11r * bxi + u11i * bxr;
  });
}

// Rot on a lane bit -- ONLY masks 8,16,32 (tid3-5)
__device__ __forceinline__ void rot_lane(v32f& ar, v32f& ai, const float* __restrict__ u,
                                         const int m, const int bit) {
  const float car = bit ? u[6] : u[0], cai = bit ? u[7] : u[1];
  const float cbr = bit ? u[4] : u[2], cbi = bit ? u[5] : u[3];
  static_for<32>([&](auto ec) {
    constexpr int e = ec.value;
    const float orr = ar[e], oii = ai[e];
    const float pr = __shfl_xor(orr, m);
    const float pi = __shfl_xor(oii, m);
    ar[e] = car * orr - cai * oii + cbr * pr - cbi * pi;
    ai[e] = car * oii + cai * orr + cbr * pi + cbi * pr;
  });
}

// CNOT, local target TB (qubit TB, P tiling: locals = a0-4); control qubit C.
template <int TB, int C>
__device__ __forceinline__ void cnot_localP(v32f& ar, v32f& ai, const int ibase) {
  static_for<16>([&](auto hc) {
    constexpr int h = hc.value;
    constexpr int e0 = ((h >> TB) << (TB + 1)) | (h & ((1 << TB) - 1));
    constexpr int e1 = e0 | (1 << TB);
    if constexpr (C < 5) {
      if constexpr ((e0 >> C) & 1) {
        const float tr = ar[e0], ti = ai[e0];
        ar[e0] = ar[e1]; ai[e0] = ai[e1];
        ar[e1] = tr;     ai[e1] = ti;
      }
    } else {
      const int take = (ibase >> C) & 1;
      const float axr = ar[e0], axi = ai[e0], bxr = ar[e1], bxi = ai[e1];
      ar[e0] = take ? bxr : axr; ai[e0] = take ? bxi : axi;
      ar[e1] = take ? axr : bxr; ai[e1] = take ? axi : bxi;
    }
  });
}

// CNOT, lane target (mask m in {8,16,32}); control qubit C (P tiling).
template <int C>
__device__ __forceinline__ void cnot_laneP(v32f& ar, v32f& ai, const int m, const int ibase) {
  if constexpr (C < 5) {
    static_for<32>([&](auto ec) {
      constexpr int e = ec.value;
      if constexpr ((e >> C) & 1) {
        ar[e] = __shfl_xor(ar[e], m);
        ai[e] = __shfl_xor(ai[e], m);
      }
    });
  } else {
    const int take = (ibase >> C) & 1;
    static_for<32>([&](auto ec) {
      constexpr int e = ec.value;
      const float pr = __shfl_xor(ar[e], m);
      const float pi = __shfl_xor(ai[e], m);
      ar[e] = take ? pr : ar[e];
      ai[e] = take ? pi : ai[e];
    });
  }
}

// ---------------- Q-side helpers: 64 amps = (b0 = a0) x (m = a8-12) ----------------

template <int J>  // Rot on m-bit J (qubit 8+J), both b0-halves
__device__ __forceinline__ void rot_m(v32f& ar0, v32f& ai0, v32f& ar1, v32f& ai1,
                                      const float* __restrict__ u) {
  const float u00r = u[0], u00i = u[1], u01r = u[2], u01i = u[3];
  const float u10r = u[4], u10i = u[5], u11r = u[6], u11i = u[7];
  static_for<16>([&](auto hc) {
    constexpr int h = hc.value;
    constexpr int m0 = ((h >> J) << (J + 1)) | (h & ((1 << J) - 1));
    constexpr int m1 = m0 | (1 << J);
    {
      const float axr = ar0[m0], axi = ai0[m0], bxr = ar0[m1], bxi = ai0[m1];
      ar0[m0] = u00r * axr - u00i * axi + u01r * bxr - u01i * bxi;
      ai0[m0] = u00r * axi + u00i * axr + u01r * bxi + u01i * bxr;
      ar0[m1] = u10r * axr - u10i * axi + u11r * bxr - u11i * bxi;
      ai0[m1] = u10r * axi + u10i * axr + u11r * bxi + u11i * bxr;
    }
    {
      const float axr = ar1[m0], axi = ai1[m0], bxr = ar1[m1], bxi = ai1[m1];
      ar1[m0] = u00r * axr - u00i * axi + u01r * bxr - u01i * bxi;
      ai1[m0] = u00r * axi + u00i * axr + u01r * bxi + u01i * bxr;
      ar1[m1] = u10r * axr - u10i * axi + u11r * bxr - u11i * bxi;
      ai1[m1] = u10r * axi + u10i * axr + u11r * bxi + u11i * bxr;
    }
  });
}

// Rot on a lane bit (masks 8,16,32), all 64 amps
__device__ __forceinline__ void rot_laneQ(v32f& ar0, v32f& ai0, v32f& ar1, v32f& ai1,
                                          const float* __restrict__ u,
                                          const int m, const int bit) {
  const float car = bit ? u[6] : u[0], cai = bit ? u[7] : u[1];
  const float cbr = bit ? u[4] : u[2], cbi = bit ? u[5] : u[3];
  static_for<32>([&](auto ec) {
    constexpr int e = ec.value;
    {
      const float orr = ar0[e], oii = ai0[e];
      const float pr = __shfl_xor(orr, m);
      const float pi = __shfl_xor(oii, m);
      ar0[e] = car * orr - cai * oii + cbr * pr - cbi * pi;
      ai0[e] = car * oii + cai * orr + cbr * pi + cbi * pr;
    }
    {
      const float orr = ar1[e], oii = ai1[e];
      const float pr = __shfl_xor(orr, m);
      const float pi = __shfl_xor(oii, m);
      ar1[e] = car * orr - cai * oii + cbr * pr - cbi * pi;
      ai1[e] = car * oii + cai * orr + cbr * pi + cbi * pr;
    }
  });
}

// CNOT, local m-bit target J (qubit 8+J); control qubit C (Q tiling).
// Static control if C in [8,12] (m-bit); else thread-uniform ibase.
template <int J, int C>
__device__ __forceinline__ void cnot_mQ(v32f& ar0, v32f& ai0, v32f& ar1, v32f& ai1,
                                        const int ibase) {
  constexpr int SB = (C >= 8 && C <= 12) ? (C - 8) : -1;
  static_for<16>([&](auto hc) {
    constexpr int h = hc.value;
    constexpr int m0 = ((h >> J) << (J + 1)) | (h & ((1 << J) - 1));
    constexpr int m1 = m0 | (1 << J);
    if constexpr (SB >= 0) {
      if constexpr ((m0 >> SB) & 1) {
        { const float tr = ar0[m0], ti = ai0[m0];
          ar0[m0] = ar0[m1]; ai0[m0] = ai0[m1]; ar0[m1] = tr; ai0[m1] = ti; }
        { const float tr = ar1[m0], ti = ai1[m0];
          ar1[m0] = ar1[m1]; ai1[m0] = ai1[m1]; ar1[m1] = tr; ai1[m1] = ti; }
      }
    } else {
      const int take = (ibase >> C) & 1;
      { const float axr = ar0[m0], axi = ai0[m0], bxr = ar0[m1], bxi = ai0[m1];
        ar0[m0] = take ? bxr : axr; ai0[m0] = take ? bxi : axi;
        ar0[m1] = take ? axr : bxr; ai0[m1] = take ? axi : bxi; }
      { const float axr = ar1[m0], axi = ai1[m0], bxr = ar1[m1], bxi = ai1[m1];
        ar1[m0] = take ? bxr : axr; ai1[m0] = take ? bxi : axi;
        ar1[m1] = take ? axr : bxr; ai1[m1] = take ? axi : bxi; }
    }
  });
}

// CNOT, lane target (mask m in {8,16,32}); control qubit C (Q tiling).
template <int C>
__device__ __forceinline__ void cnot_laneQ(v32f& ar0, v32f& ai0, v32f& ar1, v32f& ai1,
                                           const int m, const int ibase) {
  constexpr int SB = (C >= 8 && C <= 12) ? (C - 8) : -1;
  if constexpr (SB >= 0) {
    static_for<32>([&](auto ec) {
      constexpr int e = ec.value;
      if constexpr ((e >> SB) & 1) {
        ar0[e] = __shfl_xor(ar0[e], m); ai0[e] = __shfl_xor(ai0[e], m);
        ar1[e] = __shfl_xor(ar1[e], m); ai1[e] = __shfl_xor(ai1[e], m);
      }
    });
  } else {
    const int take = (ibase >> C) & 1;
    static_for<32>([&](auto ec) {
      constexpr int e = ec.value;
      { const float pr = __shfl_xor(ar0[e], m), pi = __shfl_xor(ai0[e], m);
        ar0[e] = take ? pr : ar0[e]; ai0[e] = take ? pi : ai0[e]; }
      { const float pr = __shfl_xor(ar1[e], m), pi = __shfl_xor(ai1[e], m);
        ar1[e] = take ? pr : ar1[e]; ai1[e] = take ? pi : ai1[e]; }
    });
  }
}

// ---------------- prep: 96 Rot matrices ----------------
__global__ void qsim_prep(const float* __restrict__ w, float* __restrict__ gm) {
  const int i = threadIdx.x;
  if (i < 96) {
    const float phi = w[i * 3 + 0];
    const float th  = w[i * 3 + 1];
    const float om  = w[i * 3 + 2];
    float st, ct; sincosf(0.5f * th, &st, &ct);
    float sa, ca; sincosf(0.5f * (phi + om), &sa, &ca);
    float sb, cb; sincosf(0.5f * (phi - om), &sb, &cb);
    float* u = gm + i * 8;
    u[0] =  ct * ca; u[1] = -ct * sa;   // m00
    u[2] = -st * cb; u[3] = -st * sb;   // m01
    u[4] =  st * cb; u[5] = -st * sb;   // m10
    u[6] =  ct * ca; u[7] =  ct * sa;   // m11
  }
}

// ---------------- Sweep P : rots 0-7, prefix (32 amps) ----------------
template <int L>
__global__ void __launch_bounds__(NTH) sweepP(float2* __restrict__ st,
                                              const float* __restrict__ x,
                                              const float* __restrict__ gm) {
  const int tid = threadIdx.x;
  const int s  = blockIdx.x >> 2;
  const int fb = blockIdx.x & 3;
  // amp: a0-4=e | a5-7=tid3-5 | a8-10=tid6-8 | a11-12=fb | a13-15=tid0-2
  const int ibase = (((tid >> 3) & 7) << 5) | (((tid >> 6) & 7) << 8) |
                    (fb << 11) | ((tid & 7) << 13);
  const int pbase = (((tid >> 3) & 7) << 1) | ((tid & 7) << 4) |
                    (((tid >> 6) & 7) << 11) | (fb << 14);
  float2* __restrict__ base = st + (s << 16) + pbase;
  constexpr int r = L + 1;
  const float* __restrict__ gl = gm + L * 128;
  v32f ar, ai;

  if constexpr (L == 0) {
    // init: |psi> = prod_q v_q, v_q = Rot_0(q)*RX(x_q)|0>  (ALL 16 rots folded)
    __shared__ float iv[16][4];
    if (tid < 16) {
      const float* u = gm + tid * 8;
      float sx, cx; sincosf(0.5f * x[s * 16 + tid], &sx, &cx);
      iv[tid][0] = u[0] * cx + u[3] * sx;
      iv[tid][1] = u[1] * cx - u[2] * sx;
      iv[tid][2] = u[4] * cx + u[7] * sx;
      iv[tid][3] = u[5] * cx - u[6] * sx;
    }
    __syncthreads();
    float Tr = 1.f, Ti = 0.f;
    #pragma unroll
    for (int b = 5; b <= 15; ++b) {
      const int bit = (ibase >> b) & 1;
      const float fr = iv[b][2 * bit], fi = iv[b][2 * bit + 1];
      const float nr = Tr * fr - Ti * fi; Ti = Tr * fi + Ti * fr; Tr = nr;
    }
    ar[0] = Tr; ai[0] = Ti;
    static_for<5>([&](auto bc) {
      constexpr int bI = bc.value;
      const float v0r = iv[bI][0], v0i = iv[bI][1], v1r = iv[bI][2], v1i = iv[bI][3];
      static_for<(1 << bI)>([&](auto kc) {
        constexpr int k = kc.value;
        constexpr int k1 = k | (1 << bI);
        const float kr = ar[k], ki = ai[k];
        ar[k1] = kr * v1r - ki * v1i; ai[k1] = kr * v1i + ki * v1r;
        ar[k]  = kr * v0r - ki * v0i; ai[k]  = kr * v0i + ki * v0r;
      });
    });
  } else {
    #pragma unroll
    for (int eh = 0; eh < 16; ++eh) {
      const float4 v = *reinterpret_cast<const float4*>(base + (eh << 7));
      ar[2 * eh] = v.x; ai[2 * eh] = v.y; ar[2 * eh + 1] = v.z; ai[2 * eh + 1] = v.w;
    }
    // deferred wraps of layer L-1: t=k (local, k<=4), c=16-L+k in a11-15 (ibase)
    static_for<L>([&](auto kc) {
      constexpr int k = kc.value;
      constexpr int C = 16 - L + k;
      cnot_localP<k, C>(ar, ai, ibase);
    });
    rot_local<0>(ar, ai, gl);
    rot_local<1>(ar, ai, gl + 8);
    rot_local<2>(ar, ai, gl + 16);
    rot_local<3>(ar, ai, gl + 24);
    rot_local<4>(ar, ai, gl + 32);
    rot_lane(ar, ai, gl + 40, 8,  (tid >> 3) & 1);   // R_L(5)
    rot_lane(ar, ai, gl + 48, 16, (tid >> 4) & 1);   // R_L(6)
    rot_lane(ar, ai, gl + 56, 32, (tid >> 5) & 1);   // R_L(7)
  }

  // ring prefix: g = 0..7-r, t = g+r in [r,7]
  static_for<8 - r>([&](auto gc) {
    constexpr int g = gc.value;
    constexpr int t = g + r;
    if constexpr (t <= 4) cnot_localP<t, g>(ar, ai, ibase);
    else                  cnot_laneP<g>(ar, ai, 1 << (t - 2), ibase);  // 5,6,7 -> 8,16,32
  });

  #pragma unroll
  for (int eh = 0; eh < 16; ++eh)
    *reinterpret_cast<float4*>(base + (eh << 7)) =
        make_float4(ar[2 * eh], ai[2 * eh], ar[2 * eh + 1], ai[2 * eh + 1]);
}

// ---------------- Sweep Q : rots 8-15, ring mid (64 amps) ----------------
template <int L>
__global__ void __launch_bounds__(NTH) sweepQ(float2* __restrict__ st,
                                              const float* __restrict__ gm) {
  const int tid = threadIdx.x;
  const int s  = blockIdx.x >> 1;
  const int fb = blockIdx.x & 1;
  // amp: a0,a8-12=E | a5-7=tid0-2 | a13-15=tid3-5 | a1-3=tid6-8 | a4=fb
  const int ibase = ((tid & 7) << 5) | (((tid >> 3) & 7) << 13) |
                    (((tid >> 6) & 7) << 1) | (fb << 4);
  const int pbase = ((tid & 7) << 1) | (((tid >> 3) & 7) << 4) |
                    (((tid >> 6) & 7) << 7) | (fb << 10);
  float2* __restrict__ base = st + (s << 16) + pbase;
  constexpr int r = L + 1;
  const float* __restrict__ gl = gm + L * 128;
  v32f ar0, ai0, ar1, ai1;   // element = b0(a0) | m(a8-12); a8-12 at p11-15
  #pragma unroll
  for (int m = 0; m < 32; ++m) {
    const float4 v = *reinterpret_cast<const float4*>(base + (m << 11));
    ar0[m] = v.x; ai0[m] = v.y; ar1[m] = v.z; ai1[m] = v.w;
  }
  if constexpr (L > 0) {  // layer 0's rots were folded into init
    rot_m<0>(ar0, ai0, ar1, ai1, gl + 64);                   // R_L(8)
    rot_m<1>(ar0, ai0, ar1, ai1, gl + 72);                   // R_L(9)
    rot_m<2>(ar0, ai0, ar1, ai1, gl + 80);                   // R_L(10)
    rot_m<3>(ar0, ai0, ar1, ai1, gl + 88);                   // R_L(11)
    rot_m<4>(ar0, ai0, ar1, ai1, gl + 96);                   // R_L(12)
    rot_laneQ(ar0, ai0, ar1, ai1, gl + 104, 8,  (tid >> 3) & 1);  // R_L(13)
    rot_laneQ(ar0, ai0, ar1, ai1, gl + 112, 16, (tid >> 4) & 1);  // R_L(14)
    rot_laneQ(ar0, ai0, ar1, ai1, gl + 120, 32, (tid >> 5) & 1);  // R_L(15)
  }
  // ring mid: g = 8-r..15-r, t = g+r in [8,15]
  static_for<8>([&](auto gc) {
    constexpr int g = 8 - r + gc.value;
    constexpr int t = g + r;
    if constexpr (t <= 12) cnot_mQ<t - 8, g>(ar0, ai0, ar1, ai1, ibase);
    else                   cnot_laneQ<g>(ar0, ai0, ar1, ai1, 1 << (t - 10), ibase);
  });

  #pragma unroll
  for (int m = 0; m < 32; ++m)
    *reinterpret_cast<float4*>(base + (m << 11)) =
        make_float4(ar0[m], ai0[m], ar1[m], ai1[m]);
}

// ---------------- final: wraps_5 + measurement (read-only, P-tiling) ----------------
__global__ void __launch_bounds__(NTH) finalK(const float2* __restrict__ st,
                                              float* __restrict__ part) {
  const int tid = threadIdx.x;
  const int s  = blockIdx.x >> 2;
  const int fb = blockIdx.x & 3;
  const int ibase = (((tid >> 3) & 7) << 5) | (((tid >> 6) & 7) << 8) |
                    (fb << 11) | ((tid & 7) << 13);
  const int pbase = (((tid >> 3) & 7) << 1) | ((tid & 7) << 4) |
                    (((tid >> 6) & 7) << 11) | (fb << 14);
  const float2* __restrict__ base = st + (s << 16) + pbase;
  v32f ar, ai;
  #pragma unroll
  for (int eh = 0; eh < 16; ++eh) {
    const float4 v = *reinterpret_cast<const float4*>(base + (eh << 7));
    ar[2 * eh] = v.x; ai[2 * eh] = v.y; ar[2 * eh + 1] = v.z; ai[2 * eh + 1] = v.w;
  }
  // wraps_5 (r=6): t=k (k=0..5), c=10+k (a10 wave, a11-12 fb, a13-15 tid0-2)
  static_for<6>([&](auto kc) {
    constexpr int k = kc.value;
    constexpr int C = 10 + k;
    if constexpr (k <= 4) cnot_localP<k, C>(ar, ai, ibase);
    else                  cnot_laneP<C>(ar, ai, 8, ibase);   // t=5 -> tid3 mask 8
  });
  __shared__ float red[8][16];
  float tot = 0.f, sl0 = 0.f, sl1 = 0.f, sl2 = 0.f, sl3 = 0.f, sl4 = 0.f;
  static_for<32>([&](auto ec) {
    constexpr int e = ec.value;
    const float p = ar[e] * ar[e] + ai[e] * ai[e];
    tot += p;
    if constexpr (e & 1)  sl0 -= p; else sl0 += p;
    if constexpr (e & 2)  sl1 -= p; else sl1 += p;
    if constexpr (e & 4)  sl2 -= p; else sl2 += p;
    if constexpr (e & 8)  sl3 -= p; else sl3 += p;
    if constexpr (e & 16) sl4 -= p; else sl4 += p;
  });
  const float sl[5] = {sl0, sl1, sl2, sl3, sl4};
  const int wv = tid >> 6;
  static_for<16>([&](auto qc) {
    constexpr int q = qc.value;
    float v;
    if constexpr (q < 5) v = sl[q];
    else v = ((ibase >> q) & 1) ? -tot : tot;
    v += __shfl_xor(v, 1);  v += __shfl_xor(v, 2);  v += __shfl_xor(v, 4);
    v += __shfl_xor(v, 8);  v += __shfl_xor(v, 16); v += __shfl_xor(v, 32);
    if ((tid & 63) == 0) red[wv][q] = v;
  });
  __syncthreads();
  if (tid < 16) {
    float a = 0.f;
    #pragma unroll
    for (int w8 = 0; w8 < 8; ++w8) a += red[w8][tid];
    part[blockIdx.x * 16 + tid] = a;
  }
}

// ---------------- final reduce: 4 block-partials -> out ----------------
__global__ void __launch_bounds__(NTH) reduceK(const float* __restrict__ part,
                                               float* __restrict__ out) {
  const int j = blockIdx.x * NTH + threadIdx.x;  // j = s*16 + q, j < 8192
  const int s = j >> 4, q = j & 15;
  float a = 0.f;
  #pragma unroll
  for (int f = 0; f < 4; ++f) a += part[(s << 6) + f * 16 + q];
  out[j] = a;
}

extern "C" void kernel_launch(void* const* d_in, const int* in_sizes, int n_in,
                              void* d_out, int out_size, void* d_ws, size_t ws_size,
                              hipStream_t stream) {
  (void)in_sizes; (void)n_in; (void)out_size;
  const float* x = (const float*)d_in[0];
  const float* w = (const float*)d_in[1];
  float* out = (float*)d_out;
  float* gm   = (float*)d_ws;                          // 768 floats
  float* part = (float*)((char*)d_ws + 4096);          // 512*4*16 floats = 128 KB
  float2* st  = (float2*)((char*)d_ws + 524288);       // state, chunked to fit ws

  const size_t avail = ws_size > 524288 ? ws_size - 524288 : 0;
  long long chunk = (long long)(avail / 524288);       // 512 KB per sample
  if (chunk > 256) chunk = 256;                        // 128 MB chunk
  if (chunk < 1) chunk = 1;

  qsim_prep<<<dim3(1), dim3(128), 0, stream>>>(w, gm);
  for (int s0 = 0; s0 < 512; s0 += (int)chunk) {
    const int ns = (512 - s0) < (int)chunk ? (512 - s0) : (int)chunk;
    const dim3 gp(ns * 4), gq(ns * 2), b(NTH);
    const float* xs = x + s0 * 16;
    float* pp = part + (size_t)s0 * 64;
    sweepP<0><<<gp, b, 0, stream>>>(st, xs, gm);
    sweepQ<0><<<gq, b, 0, stream>>>(st, gm);
    sweepP<1><<<gp, b, 0, stream>>>(st, xs, gm);
    sweepQ<1><<<gq, b, 0, stream>>>(st, gm);
    sweepP<2><<<gp, b, 0, stream>>>(st, xs, gm);
    sweepQ<2><<<gq, b, 0, stream>>>(st, gm);
    sweepP<3><<<gp, b, 0, stream>>>(st, xs, gm);
    sweepQ<3><<<gq, b, 0, stream>>>(st, gm);
    sweepP<4><<<gp, b, 0, stream>>>(st, xs, gm);
    sweepQ<4><<<gq, b, 0, stream>>>(st, gm);
    sweepP<5><<<gp, b, 0, stream>>>(st, xs, gm);
    sweepQ<5><<<gq, b, 0, stream>>>(st, gm);
    finalK<<<gp, b, 0, stream>>>(st, pp);
  }
  reduceK<<<dim3(16), dim3(NTH), 0, stream>>>(part, out);
}

// Round 11
// 1713.666 us; speedup vs baseline: 2.9227x; 2.9227x over previous
//
#include <hip/hip_runtime.h>

// 16-qubit statevector, 512 samples, 6 StronglyEntanglingLayers, qubit q <-> bit q.
// Round 18: round-16's verified-correct all-cheap-rot schedule with a phys
// layout satisfying the COVERAGE RULE both ways: every bit of a 128B line must
// be owned by lane bits or loop-varying local bits of the issuing wave, in
// BOTH kernels. Intersection of P/Q coverage sets = shared lane bits
// {a5-7, a13-15} -> p0-5 = those (lanes in both), p6-10 = a0-4 (P locals),
// p11-15 = a8-12 (Q locals). Every wave instruction in both kernels covers
// 512B fully contiguously (64 lanes x 8B float2). r9's Q defect (p0 = Q wave
// bit -> half-line coverage -> FETCH 115MB/WRITE 229MB/122us) is gone; r10's
// 64-amp spill (128 VGPR state -> scratch, 830MB fetch) is avoided (Q back to
// 32 amps, 2x v32f). Gate logic/ibase/schedule byte-identical to round-16
// (passed correctness); only pbase + load/store width changed.
//
// Tilings (r = l+1):
//   P(l) [32 amps]: E=a0-4 | tid3-5=a5-7 | tid0-2=a13-15 | waves=a8-10 | fb=a11-12.
//        wraps_{l-1} (t=k local, c=16-l+k), R_l(0-4) local, R_l(5-7) masks 8,16,32,
//        prefix g=0..7-r (t=r..7). ZERO rots on tid0-2.
//   Q(l) [32 amps]: E=a8-12 | tid0-2=a5-7 | tid3-5=a13-15 | waves=a0-2 | fb=a3-4.
//        R_l(8-12) local, R_l(13-15) masks 8,16,32, mid g=8-r..15-r (t=8..15).
//   P(0): init = product of Rot_0(q)*RX(x_q)|0> (all 16 rots folded) + prefix.
//   finalK: wraps_5 (t=0..5, c=10..15) + measurement. P-tiling.
// Phys: p0-2=a5-7 | p3-5=a13-15 | p6-10=a0-4 | p11-15=a8-12.
// Chunk = 256 samples (128 MB).

#define NTH 512
typedef float v32f __attribute__((ext_vector_type(32)));

template <int I> struct IC { static constexpr int value = I; };
template <int N, int I = 0, typename F>
__device__ __forceinline__ void static_for(F&& f) {
  if constexpr (I < N) { f(IC<I>{}); static_for<N, I + 1>(f); }
}

// ---------------- gate helpers on 32 reg amps ----------------

template <int LB>  // Rot on local e-bit LB; qubit = LOCALLO + LB
__device__ __forceinline__ void rot_local(v32f& ar, v32f& ai, const float* __restrict__ u) {
  const float u00r = u[0], u00i = u[1], u01r = u[2], u01i = u[3];
  const float u10r = u[4], u10i = u[5], u11r = u[6], u11i = u[7];
  static_for<16>([&](auto hc) {
    constexpr int h = hc.value;
    constexpr int e0 = ((h >> LB) << (LB + 1)) | (h & ((1 << LB) - 1));
    constexpr int e1 = e0 | (1 << LB);
    const float axr = ar[e0], axi = ai[e0], bxr = ar[e1], bxi = ai[e1];
    ar[e0] = u00r * axr - u00i * axi + u01r * bxr - u01i * bxi;
    ai[e0] = u00r * axi + u00i * axr + u01r * bxi + u01i * bxr;
    ar[e1] = u10r * axr - u10i * axi + u11r * bxr - u11i * bxi;
    ai[e1] = u10r * axi + u10i * axr + u11r * bxi + u11i * bxr;
  });
}

// Rot on a lane bit -- ONLY ever called with masks 8,16,32 (tid3-5).
__device__ __forceinline__ void rot_lane(v32f& ar, v32f& ai, const float* __restrict__ u,
                                         const int m, const int bit) {
  const float car = bit ? u[6] : u[0], cai = bit ? u[7] : u[1];
  const float cbr = bit ? u[4] : u[2], cbi = bit ? u[5] : u[3];
  static_for<32>([&](auto ec) {
    constexpr int e = ec.value;
    const float orr = ar[e], oii = ai[e];
    const float pr = __shfl_xor(orr, m);
    const float pi = __shfl_xor(oii, m);
    ar[e] = car * orr - cai * oii + cbr * pr - cbi * pi;
    ai[e] = car * oii + cai * orr + cbr * pi + cbi * pr;
  });
}

// CNOT, local e-bit target TB; LOCALLO = qubit index of e-bit 0; control qubit C.
template <int TB, int LOCALLO, int C>
__device__ __forceinline__ void cnot_local(v32f& ar, v32f& ai, const int ibase) {
  static_for<16>([&](auto hc) {
    constexpr int h = hc.value;
    constexpr int e0 = ((h >> TB) << (TB + 1)) | (h & ((1 << TB) - 1));
    constexpr int e1 = e0 | (1 << TB);
    if constexpr (C >= LOCALLO && C < LOCALLO + 5) {
      if constexpr ((e0 >> (C - LOCALLO)) & 1) {  // static: pure register swap
        const float tr = ar[e0], ti = ai[e0];
        ar[e0] = ar[e1]; ai[e0] = ai[e1];
        ar[e1] = tr;     ai[e1] = ti;
      }
    } else {
      const int take = (ibase >> C) & 1;
      const float axr = ar[e0], axi = ai[e0], bxr = ar[e1], bxi = ai[e1];
      ar[e0] = take ? bxr : axr; ai[e0] = take ? bxi : axi;
      ar[e1] = take ? axr : bxr; ai[e1] = take ? axi : bxi;
    }
  });
}

// CNOT, lane-bit target (mask m in {8,16,32}); control qubit C (C != target).
template <int LOCALLO, int C>
__device__ __forceinline__ void cnot_lane(v32f& ar, v32f& ai, const int m, const int ibase) {
  if constexpr (C >= LOCALLO && C < LOCALLO + 5) {
    static_for<32>([&](auto ec) {
      constexpr int e = ec.value;
      if constexpr ((e >> (C - LOCALLO)) & 1) {
        ar[e] = __shfl_xor(ar[e], m);
        ai[e] = __shfl_xor(ai[e], m);
      }
    });
  } else {
    const int take = (ibase >> C) & 1;
    static_for<32>([&](auto ec) {
      constexpr int e = ec.value;
      const float pr = __shfl_xor(ar[e], m);
      const float pi = __shfl_xor(ai[e], m);
      ar[e] = take ? pr : ar[e];
      ai[e] = take ? pi : ai[e];
    });
  }
}

// ---------------- prep: 96 Rot matrices ----------------
__global__ void qsim_prep(const float* __restrict__ w, float* __restrict__ gm) {
  const int i = threadIdx.x;
  if (i < 96) {
    const float phi = w[i * 3 + 0];
    const float th  = w[i * 3 + 1];
    const float om  = w[i * 3 + 2];
    float st, ct; sincosf(0.5f * th, &st, &ct);
    float sa, ca; sincosf(0.5f * (phi + om), &sa, &ca);
    float sb, cb; sincosf(0.5f * (phi - om), &sb, &cb);
    float* u = gm + i * 8;
    u[0] =  ct * ca; u[1] = -ct * sa;   // m00
    u[2] = -st * cb; u[3] = -st * sb;   // m01
    u[4] =  st * cb; u[5] = -st * sb;   // m10
    u[6] =  ct * ca; u[7] =  ct * sa;   // m11
  }
}

// ---------------- Sweep P : rots 0-7, prefix (32 amps) ----------------
template <int L>
__global__ void __launch_bounds__(NTH) sweepP(float2* __restrict__ st,
                                              const float* __restrict__ x,
                                              const float* __restrict__ gm) {
  const int tid = threadIdx.x;
  const int s  = blockIdx.x >> 2;
  const int fb = blockIdx.x & 3;
  // amp: a0-4=e | a5-7=tid3-5 | a8-10=tid6-8 | a11-12=fb | a13-15=tid0-2
  const int ibase = (((tid >> 3) & 7) << 5) | (((tid >> 6) & 7) << 8) |
                    (fb << 11) | ((tid & 7) << 13);
  // phys: a5-7->p0-2 | a13-15->p3-5 | a0-4->p6-10 (loop) | a8-10->p11-13 | a11-12->p14-15
  const int pbase = ((tid >> 3) & 7) | ((tid & 7) << 3) |
                    (((tid >> 6) & 7) << 11) | (fb << 14);
  float2* __restrict__ base = st + (s << 16) + pbase;
  constexpr int r = L + 1;
  const float* __restrict__ gl = gm + L * 128;
  v32f ar, ai;

  if constexpr (L == 0) {
    // init: |psi> = prod_q v_q, v_q = Rot_0(q)*RX(x_q)|0>  (ALL 16 rots folded)
    __shared__ float iv[16][4];
    if (tid < 16) {
      const float* u = gm + tid * 8;
      float sx, cx; sincosf(0.5f * x[s * 16 + tid], &sx, &cx);
      iv[tid][0] = u[0] * cx + u[3] * sx;
      iv[tid][1] = u[1] * cx - u[2] * sx;
      iv[tid][2] = u[4] * cx + u[7] * sx;
      iv[tid][3] = u[5] * cx - u[6] * sx;
    }
    __syncthreads();
    float Tr = 1.f, Ti = 0.f;
    #pragma unroll
    for (int b = 5; b <= 15; ++b) {
      const int bit = (ibase >> b) & 1;
      const float fr = iv[b][2 * bit], fi = iv[b][2 * bit + 1];
      const float nr = Tr * fr - Ti * fi; Ti = Tr * fi + Ti * fr; Tr = nr;
    }
    ar[0] = Tr; ai[0] = Ti;
    static_for<5>([&](auto bc) {
      constexpr int bI = bc.value;
      const float v0r = iv[bI][0], v0i = iv[bI][1], v1r = iv[bI][2], v1i = iv[bI][3];
      static_for<(1 << bI)>([&](auto kc) {
        constexpr int k = kc.value;
        constexpr int k1 = k | (1 << bI);
        const float kr = ar[k], ki = ai[k];
        ar[k1] = kr * v1r - ki * v1i; ai[k1] = kr * v1i + ki * v1r;
        ar[k]  = kr * v0r - ki * v0i; ai[k]  = kr * v0i + ki * v0r;
      });
    });
  } else {
    #pragma unroll
    for (int e = 0; e < 32; ++e) {
      const float2 v = base[e << 6];
      ar[e] = v.x; ai[e] = v.y;
    }
    // deferred wraps of layer L-1: t=k (local), c=16-L+k in a11-15 (ibase)
    static_for<L>([&](auto kc) {
      constexpr int k = kc.value;
      constexpr int C = 16 - L + k;
      cnot_local<k, 0, C>(ar, ai, ibase);
    });
    rot_local<0>(ar, ai, gl);
    rot_local<1>(ar, ai, gl + 8);
    rot_local<2>(ar, ai, gl + 16);
    rot_local<3>(ar, ai, gl + 24);
    rot_local<4>(ar, ai, gl + 32);
    rot_lane(ar, ai, gl + 40, 8,  (tid >> 3) & 1);   // R_L(5)
    rot_lane(ar, ai, gl + 48, 16, (tid >> 4) & 1);   // R_L(6)
    rot_lane(ar, ai, gl + 56, 32, (tid >> 5) & 1);   // R_L(7)
  }

  // ring prefix: g = 0..7-r, t = g+r in [r,7]
  static_for<8 - r>([&](auto gc) {
    constexpr int g = gc.value;
    constexpr int t = g + r;
    if constexpr (t <= 4) cnot_local<t, 0, g>(ar, ai, ibase);
    else                  cnot_lane<0, g>(ar, ai, 1 << (t - 2), ibase);  // 5,6,7 -> 8,16,32
  });

  #pragma unroll
  for (int e = 0; e < 32; ++e) {
    float2 v; v.x = ar[e]; v.y = ai[e];
    base[e << 6] = v;
  }
}

// ---------------- Sweep Q : rots 8-15, ring mid (32 amps) ----------------
template <int L>
__global__ void __launch_bounds__(NTH) sweepQ(float2* __restrict__ st,
                                              const float* __restrict__ gm) {
  const int tid = threadIdx.x;
  const int s  = blockIdx.x >> 2;
  const int fb = blockIdx.x & 3;
  // amp: a8-12=e | a5-7=tid0-2 | a13-15=tid3-5 | a0-2=tid6-8 | a3-4=fb
  const int ibase = ((tid >> 6) & 7) | (fb << 3) | ((tid & 7) << 5) |
                    (((tid >> 3) & 7) << 13);
  // phys: a5-7->p0-2 | a13-15->p3-5 | a0-2->p6-8 | a3-4->p9-10 | a8-12->p11-15 (loop)
  const int pbase = (tid & 7) | (((tid >> 3) & 7) << 3) |
                    (((tid >> 6) & 7) << 6) | (fb << 9);
  float2* __restrict__ base = st + (s << 16) + pbase;
  constexpr int r = L + 1;
  const float* __restrict__ gl = gm + L * 128;
  v32f ar, ai;
  #pragma unroll
  for (int e = 0; e < 32; ++e) {
    const float2 v = base[e << 11];
    ar[e] = v.x; ai[e] = v.y;
  }
  if constexpr (L > 0) {  // layer 0's rots were folded into init
    rot_local<0>(ar, ai, gl + 64);                   // R_L(8)
    rot_local<1>(ar, ai, gl + 72);                   // R_L(9)
    rot_local<2>(ar, ai, gl + 80);                   // R_L(10)
    rot_local<3>(ar, ai, gl + 88);                   // R_L(11)
    rot_local<4>(ar, ai, gl + 96);                   // R_L(12)
    rot_lane(ar, ai, gl + 104, 8,  (tid >> 3) & 1);  // R_L(13)
    rot_lane(ar, ai, gl + 112, 16, (tid >> 4) & 1);  // R_L(14)
    rot_lane(ar, ai, gl + 120, 32, (tid >> 5) & 1);  // R_L(15)
  }
  // ring mid: g = 8-r..15-r, t = g+r in [8,15]
  static_for<8>([&](auto gc) {
    constexpr int g = 8 - r + gc.value;
    constexpr int t = g + r;
    if constexpr (t <= 12) cnot_local<t - 8, 8, g>(ar, ai, ibase);
    else                   cnot_lane<8, g>(ar, ai, 1 << (t - 10), ibase);  // 13,14,15 -> 8,16,32
  });

  #pragma unroll
  for (int e = 0; e < 32; ++e) {
    float2 v; v.x = ar[e]; v.y = ai[e];
    base[e << 11] = v;
  }
}

// ---------------- final: wraps_5 + measurement (read-only, P-tiling) ----------------
__global__ void __launch_bounds__(NTH) finalK(const float2* __restrict__ st,
                                              float* __restrict__ part) {
  const int tid = threadIdx.x;
  const int s  = blockIdx.x >> 2;
  const int fb = blockIdx.x & 3;
  const int ibase = (((tid >> 3) & 7) << 5) | (((tid >> 6) & 7) << 8) |
                    (fb << 11) | ((tid & 7) << 13);
  const int pbase = ((tid >> 3) & 7) | ((tid & 7) << 3) |
                    (((tid >> 6) & 7) << 11) | (fb << 14);
  const float2* __restrict__ base = st + (s << 16) + pbase;
  v32f ar, ai;
  #pragma unroll
  for (int e = 0; e < 32; ++e) {
    const float2 v = base[e << 6];
    ar[e] = v.x; ai[e] = v.y;
  }
  // wraps_5 (r=6): t=k (k=0..5), c=10+k (a10 wave, a11-12 fb, a13-15 tid0-2)
  static_for<6>([&](auto kc) {
    constexpr int k = kc.value;
    constexpr int C = 10 + k;
    if constexpr (k <= 4) cnot_local<k, 0, C>(ar, ai, ibase);
    else                  cnot_lane<0, C>(ar, ai, 8, ibase);   // t=5 -> tid3 mask 8
  });
  __shared__ float red[8][16];
  float tot = 0.f, sl0 = 0.f, sl1 = 0.f, sl2 = 0.f, sl3 = 0.f, sl4 = 0.f;
  static_for<32>([&](auto ec) {
    constexpr int e = ec.value;
    const float p = ar[e] * ar[e] + ai[e] * ai[e];
    tot += p;
    if constexpr (e & 1)  sl0 -= p; else sl0 += p;
    if constexpr (e & 2)  sl1 -= p; else sl1 += p;
    if constexpr (e & 4)  sl2 -= p; else sl2 += p;
    if constexpr (e & 8)  sl3 -= p; else sl3 += p;
    if constexpr (e & 16) sl4 -= p; else sl4 += p;
  });
  const float sl[5] = {sl0, sl1, sl2, sl3, sl4};
  const int wv = tid >> 6;
  static_for<16>([&](auto qc) {
    constexpr int q = qc.value;
    float v;
    if constexpr (q < 5) v = sl[q];
    else v = ((ibase >> q) & 1) ? -tot : tot;
    v += __shfl_xor(v, 1);  v += __shfl_xor(v, 2);  v += __shfl_xor(v, 4);
    v += __shfl_xor(v, 8);  v += __shfl_xor(v, 16); v += __shfl_xor(v, 32);
    if ((tid & 63) == 0) red[wv][q] = v;
  });
  __syncthreads();
  if (tid < 16) {
    float a = 0.f;
    #pragma unroll
    for (int w8 = 0; w8 < 8; ++w8) a += red[w8][tid];
    part[blockIdx.x * 16 + tid] = a;
  }
}

// ---------------- final reduce: 4 block-partials -> out ----------------
__global__ void __launch_bounds__(NTH) reduceK(const float* __restrict__ part,
                                               float* __restrict__ out) {
  const int j = blockIdx.x * NTH + threadIdx.x;  // j = s*16 + q, j < 8192
  const int s = j >> 4, q = j & 15;
  float a = 0.f;
  #pragma unroll
  for (int f = 0; f < 4; ++f) a += part[(s << 6) + f * 16 + q];
  out[j] = a;
}

extern "C" void kernel_launch(void* const* d_in, const int* in_sizes, int n_in,
                              void* d_out, int out_size, void* d_ws, size_t ws_size,
                              hipStream_t stream) {
  (void)in_sizes; (void)n_in; (void)out_size;
  const float* x = (const float*)d_in[0];
  const float* w = (const float*)d_in[1];
  float* out = (float*)d_out;
  float* gm   = (float*)d_ws;                          // 768 floats
  float* part = (float*)((char*)d_ws + 4096);          // 512*4*16 floats = 128 KB
  float2* st  = (float2*)((char*)d_ws + 524288);       // state, chunked to fit ws

  const size_t avail = ws_size > 524288 ? ws_size - 524288 : 0;
  long long chunk = (long long)(avail / 524288);       // 512 KB per sample
  if (chunk > 256) chunk = 256;                        // 128 MB chunk
  if (chunk < 1) chunk = 1;

  qsim_prep<<<dim3(1), dim3(128), 0, stream>>>(w, gm);
  for (int s0 = 0; s0 < 512; s0 += (int)chunk) {
    const int ns = (512 - s0) < (int)chunk ? (512 - s0) : (int)chunk;
    const dim3 g(ns * 4), b(NTH);
    const float* xs = x + s0 * 16;
    float* pp = part + (size_t)s0 * 64;
    sweepP<0><<<g, b, 0, stream>>>(st, xs, gm);
    sweepQ<0><<<g, b, 0, stream>>>(st, gm);
    sweepP<1><<<g, b, 0, stream>>>(st, xs, gm);
    sweepQ<1><<<g, b, 0, stream>>>(st, gm);
    sweepP<2><<<g, b, 0, stream>>>(st, xs, gm);
    sweepQ<2><<<g, b, 0, stream>>>(st, gm);
    sweepP<3><<<g, b, 0, stream>>>(st, xs, gm);
    sweepQ<3><<<g, b, 0, stream>>>(st, gm);
    sweepP<4><<<g, b, 0, stream>>>(st, xs, gm);
    sweepQ<4><<<g, b, 0, stream>>>(st, gm);
    sweepP<5><<<g, b, 0, stream>>>(st, xs, gm);
    sweepQ<5><<<g, b, 0, stream>>>(st, gm);
    finalK<<<g, b, 0, stream>>>(st, pp);
  }
  reduceK<<<dim3(16), dim3(NTH), 0, stream>>>(part, out);
}